// Round 1
// baseline (899.783 us; speedup 1.0000x reference)
//
#include <hip/hip_runtime.h>
#include <math.h>

#define CAP 2048
#define PRNG_PARTITIONABLE 1   // JAX >= 0.5.0 default (threefry_partitionable)

// ---------- helpers ----------
__device__ __forceinline__ unsigned int f2ord(float x) {
  // order-preserving float->uint map (ascending float -> ascending uint)
  unsigned int u = __float_as_uint(x);
  return (u & 0x80000000u) ? ~u : (u | 0x80000000u);
}

__device__ __forceinline__ unsigned int rotl_u32(unsigned int x, int r) {
  return (x << r) | (x >> (32 - r));
}

// Exact replication of jax.random.uniform(key(42), ..., 1e-20, 1.0) -> gumbel
// for flat element index `flat` of the (B,V) array.
__device__ float gumbel_at(unsigned int flat, unsigned int half_n) {
  const unsigned int ks0 = 0u;          // key hi word of seed 42
  const unsigned int ks1 = 42u;         // key lo word
  const unsigned int ks2 = 0x1BD11BDAu ^ ks0 ^ ks1;
  unsigned int x0, x1;
#if PRNG_PARTITIONABLE
  x0 = 0u;      // high 32 bits of uint64 iota
  x1 = flat;    // low 32 bits
#else
  unsigned int cnt = (flat < half_n) ? flat : (flat - half_n);
  x0 = cnt; x1 = cnt + half_n;
#endif
  x0 += ks0; x1 += ks1;
#define TF_R(r) { x0 += x1; x1 = rotl_u32(x1, r); x1 ^= x0; }
  TF_R(13) TF_R(15) TF_R(26) TF_R(6)
  x0 += ks1; x1 += ks2 + 1u;
  TF_R(17) TF_R(29) TF_R(16) TF_R(24)
  x0 += ks2; x1 += ks0 + 2u;
  TF_R(13) TF_R(15) TF_R(26) TF_R(6)
  x0 += ks0; x1 += ks1 + 3u;
  TF_R(17) TF_R(29) TF_R(16) TF_R(24)
  x0 += ks1; x1 += ks2 + 4u;
  TF_R(13) TF_R(15) TF_R(26) TF_R(6)
  x0 += ks2; x1 += ks0 + 5u;
#undef TF_R
#if PRNG_PARTITIONABLE
  unsigned int bits = x0 ^ x1;
#else
  unsigned int bits = (flat < half_n) ? x0 : x1;
#endif
  // uniform: bitcast(bits>>9 | 0x3f800000) - 1 ; u = max(1e-20, f*(1-1e-20)+1e-20)
  float f = __uint_as_float(0x3f800000u | (bits >> 9)) - 1.0f;
  float u = fmaxf(1e-20f, f + 1e-20f);
  return -logf(-logf(u));
}

// ---------- K0: gather last-token hidden rows ----------
__global__ void gather_h(const float* __restrict__ hidden, const int* __restrict__ lti,
                         float* __restrict__ hg, int D) {
  int b = blockIdx.x;
  int src = lti[b];
  const float4* s = (const float4*)(hidden + (size_t)src * D);
  float4* d = (float4*)(hg + (size_t)b * D);
  for (int i = threadIdx.x; i < D / 4; i += blockDim.x) d[i] = s[i];
}

// ---------- K1: logits = hg @ E^T  (f32 VALU GEMM, 64x64x64 tiles) ----------
#define BN 64
#define BK 64
__global__ __launch_bounds__(256) void gemm_logits(
    const float* __restrict__ hg, const float* __restrict__ E,
    float* __restrict__ outL, int B, int D, int V) {
  __shared__ float As[BK][68];  // [k][b], pad 68 keeps 16B alignment per row
  __shared__ float Bs[BK][68];  // [k][v]
  const int v0 = blockIdx.x * BN;
  const int tid = threadIdx.x;
  const int tx = tid & 15, ty = tid >> 4;
  float acc[4][4] = {{0.f, 0.f, 0.f, 0.f}, {0.f, 0.f, 0.f, 0.f},
                     {0.f, 0.f, 0.f, 0.f}, {0.f, 0.f, 0.f, 0.f}};
  for (int k0 = 0; k0 < D; k0 += BK) {
#pragma unroll
    for (int q = 0; q < 4; ++q) {
      int idx = q * 256 + tid;
      int r = idx >> 4, c4 = idx & 15;
      int rb = r < B ? r : B - 1;
      const float4 a = *(const float4*)(hg + (size_t)rb * D + k0 + c4 * 4);
      As[c4 * 4 + 0][r] = a.x; As[c4 * 4 + 1][r] = a.y;
      As[c4 * 4 + 2][r] = a.z; As[c4 * 4 + 3][r] = a.w;
      int v = v0 + r; if (v >= V) v = V - 1;
      const float4 bb = *(const float4*)(E + (size_t)v * D + k0 + c4 * 4);
      Bs[c4 * 4 + 0][r] = bb.x; Bs[c4 * 4 + 1][r] = bb.y;
      Bs[c4 * 4 + 2][r] = bb.z; Bs[c4 * 4 + 3][r] = bb.w;
    }
    __syncthreads();
#pragma unroll 16
    for (int k = 0; k < BK; ++k) {
      const float4 a = *(const float4*)&As[k][ty * 4];
      const float4 b = *(const float4*)&Bs[k][tx * 4];
      acc[0][0] += a.x * b.x; acc[0][1] += a.x * b.y; acc[0][2] += a.x * b.z; acc[0][3] += a.x * b.w;
      acc[1][0] += a.y * b.x; acc[1][1] += a.y * b.y; acc[1][2] += a.y * b.z; acc[1][3] += a.y * b.w;
      acc[2][0] += a.z * b.x; acc[2][1] += a.z * b.y; acc[2][2] += a.z * b.z; acc[2][3] += a.z * b.w;
      acc[3][0] += a.w * b.x; acc[3][1] += a.w * b.y; acc[3][2] += a.w * b.z; acc[3][3] += a.w * b.w;
    }
    __syncthreads();
  }
#pragma unroll
  for (int i = 0; i < 4; ++i) {
    int bb = ty * 4 + i;
    if (bb < B) {
      int vc = v0 + tx * 4;
      if (vc + 3 < V) {
        float4 r = make_float4(acc[i][0], acc[i][1], acc[i][2], acc[i][3]);
        *(float4*)(outL + (size_t)bb * V + vc) = r;
      } else {
        for (int j = 0; j < 4; ++j)
          if (vc + j < V) outL[(size_t)bb * V + vc + j] = acc[i][j];
      }
    }
  }
}

// ---------- K2: per-batch radix-select of k-th largest + candidate gather ----------
__global__ __launch_bounds__(1024) void select_topk(
    const float* __restrict__ logits, const int* __restrict__ top_ks,
    float* __restrict__ cvals, int* __restrict__ cidx, int* __restrict__ ccnt, int V) {
  const int b = blockIdx.x;
  const float* row = logits + (size_t)b * V;
  const int tid = threadIdx.x;
  const int wv = tid >> 6;  // wave id (16 waves)
  __shared__ unsigned int hist[16][256];
  __shared__ unsigned int s_prefix;
  __shared__ int s_needed;
  __shared__ int s_cnt;

  int k = top_ks[b];
  if (k < 1) k = 1;
  if (k > V) k = V;

  unsigned int prefix = 0;
  int needed = k;
  for (int pass = 0; pass < 4; ++pass) {
    for (int i = tid; i < 16 * 256; i += 1024) ((unsigned int*)hist)[i] = 0u;
    __syncthreads();
    const int shift = 24 - 8 * pass;
    for (int v = tid; v < V; v += 1024) {
      unsigned int u = f2ord(row[v]);
      bool ok = (pass == 0) || ((u >> (shift + 8)) == prefix);
      if (ok) atomicAdd(&hist[wv][(u >> shift) & 255u], 1u);
    }
    __syncthreads();
    if (tid < 256) {
      unsigned int s = 0;
      for (int w = 0; w < 16; ++w) s += hist[w][tid];
      hist[0][tid] = s;
    }
    __syncthreads();
    if (tid == 0) {
      unsigned int run = 0;
      int bin = 255;
      for (; bin >= 0; --bin) {
        unsigned int h = hist[0][bin];
        if (run + h >= (unsigned int)needed) break;
        run += h;
      }
      if (bin < 0) bin = 0;  // defensive; cannot happen (total >= needed)
      s_prefix = (prefix << 8) | (unsigned int)bin;
      s_needed = needed - (int)run;
    }
    __syncthreads();
    prefix = s_prefix;
    needed = s_needed;
    __syncthreads();
  }
  const unsigned int tau = prefix;  // full 32-bit ordered key of the k-th largest

  if (tid == 0) s_cnt = 0;
  __syncthreads();
  for (int v = tid; v < V; v += 1024) {
    float x = row[v];
    if (f2ord(x) >= tau) {
      int p = atomicAdd(&s_cnt, 1);
      if (p < CAP) {
        cvals[(size_t)b * CAP + p] = x;
        cidx[(size_t)b * CAP + p] = v;
      }
    }
  }
  __syncthreads();
  if (tid == 0) ccnt[b] = (s_cnt < CAP) ? s_cnt : CAP;
}

// ---------- K3: sort candidates, top-p, probs scatter, gumbel argmax ----------
__global__ __launch_bounds__(1024) void finalize_k(
    const float* __restrict__ cvals, const int* __restrict__ cidx,
    const int* __restrict__ ccnt, const int* __restrict__ top_ks,
    const float* __restrict__ temps, const float* __restrict__ top_ps,
    float* __restrict__ out, int probs_base, int V, unsigned int half_n) {
  const int b = blockIdx.x, tid = threadIdx.x;
  __shared__ float vals[CAP];
  __shared__ int idxs[CAP];
  __shared__ float ex[1024];
  __shared__ float pr[1024];
  __shared__ float rsc[1024];
  __shared__ int rid[1024];
  __shared__ float s_S, s_S2;
  __shared__ int s_m;

  const int cnt = ccnt[b];
  int k = top_ks[b];
  if (k < 1) k = 1;
  if (k > V) k = V;
  int K = (k < cnt) ? k : cnt;
  if (K > 1024) K = 1024;  // inputs guarantee k <= 1023

  for (int i = tid; i < CAP; i += 1024) {
    if (i < cnt) { vals[i] = cvals[(size_t)b * CAP + i]; idxs[i] = cidx[(size_t)b * CAP + i]; }
    else         { vals[i] = -INFINITY;                  idxs[i] = 0x7fffffff; }
  }
  __syncthreads();

  // bitonic sort: (val desc, idx asc) == argsort(-logits) stable order
  for (int size = 2; size <= CAP; size <<= 1) {
    for (int stride = size >> 1; stride > 0; stride >>= 1) {
      for (int i = tid; i < CAP; i += 1024) {
        int j = i ^ stride;
        if (j > i) {
          float vi = vals[i], vj = vals[j];
          int ii = idxs[i], ij = idxs[j];
          bool iBeforeJ = (vi > vj) || (vi == vj && ii < ij);
          bool up = ((i & size) == 0);
          if (up ? !iBeforeJ : iBeforeJ) {
            vals[i] = vj; idxs[i] = ij; vals[j] = vi; idxs[j] = ii;
          }
        }
      }
      __syncthreads();
    }
  }

  const float t = temps[b];
  const float tt = (t < 1e-5f) ? 1.0f : t;
  const float l0 = vals[0] / tt;
  for (int i = tid; i < K; i += 1024) ex[i] = expf(vals[i] / tt - l0);
  __syncthreads();

  if (tid == 0) {  // sequential f32 softmax denominator over top-k
    float S = 0.f;
    for (int i = 0; i < K; ++i) S += ex[i];
    s_S = S;
  }
  __syncthreads();
  const float S = s_S;
  for (int i = tid; i < K; i += 1024) pr[i] = ex[i] / S;
  __syncthreads();

  if (tid == 0) {  // sequential cumsum -> top-p prefix length m
    float p = top_ps[b];
    int m;
    if (p >= 1.0f - 1e-5f) m = K;
    else {
      m = 1;
      float cum = pr[0];
      for (int i = 1; i < K; ++i) {
        cum += pr[i];
        if (cum <= p) m++; else break;
      }
    }
    s_m = m;
  }
  __syncthreads();
  const int m = s_m;

  // final softmax denominator over kept set (parallel reduce; tolerance is huge)
  {
    float loc = 0.f;
    for (int i = tid; i < m; i += 1024) loc += ex[i];
    rsc[tid] = loc;
    __syncthreads();
    for (int s = 512; s > 0; s >>= 1) {
      if (tid < s) rsc[tid] += rsc[tid + s];
      __syncthreads();
    }
    if (tid == 0) s_S2 = rsc[0];
    __syncthreads();
  }
  const float S2 = s_S2;

  // scatter probs
  for (int i = tid; i < m; i += 1024)
    out[(size_t)probs_base + (size_t)b * V + idxs[i]] = ex[i] / S2;

  // gumbel-max over kept set
  float best = -INFINITY;
  int bestV = 0x7fffffff;
  for (int i = tid; i < m; i += 1024) {
    int vv = idxs[i];
    unsigned int flat = (unsigned int)b * (unsigned int)V + (unsigned int)vv;
    float g = gumbel_at(flat, half_n);
    float sc = vals[i] / tt + g;
    if (sc > best || (sc == best && vv < bestV)) { best = sc; bestV = vv; }
  }
  rsc[tid] = best; rid[tid] = bestV;
  __syncthreads();
  for (int s = 512; s > 0; s >>= 1) {
    if (tid < s) {
      float o = rsc[tid + s]; int oi = rid[tid + s];
      if (o > rsc[tid] || (o == rsc[tid] && oi < rid[tid])) { rsc[tid] = o; rid[tid] = oi; }
    }
    __syncthreads();
  }
  if (tid == 0) {
    int token = (t < 1e-5f) ? idxs[0] : rid[0];  // greedy = global argmax (sorted[0])
    if (token < 0 || token >= V) token = 0;
    out[b] = (float)token;
  }
}

// ---------- launch ----------
extern "C" void kernel_launch(void* const* d_in, const int* in_sizes, int n_in,
                              void* d_out, int out_size, void* d_ws, size_t ws_size,
                              hipStream_t stream) {
  const float* hidden = (const float*)d_in[0];
  const float* emb    = (const float*)d_in[1];
  const int*   lti    = (const int*)d_in[2];
  const float* temps  = (const float*)d_in[3];
  const float* tops   = (const float*)d_in[4];
  const int*   topks  = (const int*)d_in[5];

  const int B = in_sizes[2];
  const int V = (int)(((long long)out_size - B) / B);
  const int D = in_sizes[1] / V;
  const int probs_base = out_size - B * V;  // = B
  const unsigned int half_n = (unsigned int)(((long long)B * V) / 2);

  float* out = (float*)d_out;

  // workspace layout
  char* ws = (char*)d_ws;
  size_t off = 0;
  float* hg = (float*)(ws + off);    off += (size_t)B * D * sizeof(float);
  float* cvals = (float*)(ws + off); off += (size_t)B * CAP * sizeof(float);
  int* cidx = (int*)(ws + off);      off += (size_t)B * CAP * sizeof(int);
  int* ccnt = (int*)(ws + off);      off += (size_t)B * sizeof(int);
  (void)ws_size; (void)n_in;

  float* logits = out + probs_base;  // stage raw dots in the probs region

  hipLaunchKernelGGL(gather_h, dim3(B), dim3(256), 0, stream, hidden, lti, hg, D);
  const int nblk = (V + BN - 1) / BN;
  hipLaunchKernelGGL(gemm_logits, dim3(nblk), dim3(256), 0, stream, hg, emb, logits, B, D, V);
  hipLaunchKernelGGL(select_topk, dim3(B), dim3(1024), 0, stream, logits, topks, cvals, cidx, ccnt, V);
  hipMemsetAsync(d_out, 0, (size_t)out_size * sizeof(float), stream);
  hipLaunchKernelGGL(finalize_k, dim3(B), dim3(1024), 0, stream, cvals, cidx, ccnt,
                     topks, temps, tops, out, probs_base, V, half_n);
}

// Round 2
// 555.386 us; speedup vs baseline: 1.6201x; 1.6201x over previous
//
#include <hip/hip_runtime.h>
#include <hip/hip_bf16.h>
#include <math.h>

#define CAP 2048
#define PRNG_PARTITIONABLE 1   // JAX >= 0.5.0 default (threefry_partitionable)

typedef __attribute__((ext_vector_type(8))) short bf16x8;
typedef __attribute__((ext_vector_type(4))) float f32x4;
typedef __attribute__((ext_vector_type(4))) unsigned int u32x4;

// ---------- helpers ----------
__device__ __forceinline__ unsigned int f2ord(float x) {
  unsigned int u = __float_as_uint(x);
  return (u & 0x80000000u) ? ~u : (u | 0x80000000u);
}

__device__ __forceinline__ unsigned int rotl_u32(unsigned int x, int r) {
  return (x << r) | (x >> (32 - r));
}

__device__ float gumbel_at(unsigned int flat, unsigned int half_n) {
  const unsigned int ks0 = 0u;
  const unsigned int ks1 = 42u;
  const unsigned int ks2 = 0x1BD11BDAu ^ ks0 ^ ks1;
  unsigned int x0, x1;
#if PRNG_PARTITIONABLE
  x0 = 0u;
  x1 = flat;
#else
  unsigned int cnt = (flat < half_n) ? flat : (flat - half_n);
  x0 = cnt; x1 = cnt + half_n;
#endif
  x0 += ks0; x1 += ks1;
#define TF_R(r) { x0 += x1; x1 = rotl_u32(x1, r); x1 ^= x0; }
  TF_R(13) TF_R(15) TF_R(26) TF_R(6)
  x0 += ks1; x1 += ks2 + 1u;
  TF_R(17) TF_R(29) TF_R(16) TF_R(24)
  x0 += ks2; x1 += ks0 + 2u;
  TF_R(13) TF_R(15) TF_R(26) TF_R(6)
  x0 += ks0; x1 += ks1 + 3u;
  TF_R(17) TF_R(29) TF_R(16) TF_R(24)
  x0 += ks1; x1 += ks2 + 4u;
  TF_R(13) TF_R(15) TF_R(26) TF_R(6)
  x0 += ks2; x1 += ks0 + 5u;
#undef TF_R
#if PRNG_PARTITIONABLE
  unsigned int bits = x0 ^ x1;
#else
  unsigned int bits = (flat < half_n) ? x0 : x1;
#endif
  float f = __uint_as_float(0x3f800000u | (bits >> 9)) - 1.0f;
  float u = fmaxf(1e-20f, f + 1e-20f);
  return -logf(-logf(u));
}

__device__ __forceinline__ unsigned short f32_to_bf16_rne(float x) {
  unsigned int u = __float_as_uint(x);
  unsigned int r = u + 0x7fffu + ((u >> 16) & 1u);
  return (unsigned short)(r >> 16);
}
__device__ __forceinline__ float bf16u_to_f32(unsigned short h) {
  return __uint_as_float(((unsigned int)h) << 16);
}

// pack 2 f32 -> bf16 hi-pair and lo-pair (residual), as u32 words
__device__ __forceinline__ void cvt_pair(float a, float b, unsigned int& h, unsigned int& l) {
  float2 xf = make_float2(a, b);
  __hip_bfloat162 hh = __float22bfloat162_rn(xf);
  float2 hf = __bfloat1622float2(hh);
  __hip_bfloat162 ll = __float22bfloat162_rn(make_float2(a - hf.x, b - hf.y));
  __builtin_memcpy(&h, &hh, 4);
  __builtin_memcpy(&l, &ll, 4);
}

__device__ __forceinline__ f32x4 mfma16(bf16x8 a, bf16x8 b, f32x4 c) {
  return __builtin_amdgcn_mfma_f32_16x16x32_bf16(a, b, c, 0, 0, 0);
}

// ---------- K0: gather last-token rows + split to bf16 hi/lo ----------
__global__ void gather_split(const float* __restrict__ hidden, const int* __restrict__ lti,
                             unsigned short* __restrict__ Ah, unsigned short* __restrict__ Al,
                             int D) {
  int b = blockIdx.x;
  const float* src = hidden + (size_t)lti[b] * D;
  for (int i = threadIdx.x; i < D; i += blockDim.x) {
    float x = src[i];
    unsigned short h = f32_to_bf16_rne(x);
    float r = x - bf16u_to_f32(h);
    Ah[(size_t)b * D + i] = h;
    Al[(size_t)b * D + i] = f32_to_bf16_rne(r);
  }
}

// ---------- K1: logits = A @ E^T via bf16x3 MFMA ----------
// BM=64 (all batches), BN=256, BK=64. 4 waves; wave w owns n in [w*64, w*64+64).
// LDS tiles bf16 [rows][64k] with 16B-granule XOR swizzle: gran_phys = o ^ (row&7).
#define BN 256
#define BK 64
__global__ __launch_bounds__(256, 2) void gemm_mfma(
    const unsigned short* __restrict__ Ahg, const unsigned short* __restrict__ Alg,
    const float* __restrict__ E, float* __restrict__ outL, int D, int V) {
  __shared__ __align__(16) unsigned short AhS[64 * 64];
  __shared__ __align__(16) unsigned short AlS[64 * 64];
  __shared__ __align__(16) unsigned short BhS[256 * 64];
  __shared__ __align__(16) unsigned short BlS[256 * 64];

  const int t = threadIdx.x;
  const int lane = t & 63;
  const int wv = t >> 6;
  const int n0 = blockIdx.x * BN;

  f32x4 acc[4][4];
#pragma unroll
  for (int i = 0; i < 4; ++i)
#pragma unroll
    for (int j = 0; j < 4; ++j) acc[i][j] = (f32x4){0.f, 0.f, 0.f, 0.f};

  f32x4 breg[16];

  // prologue: issue loads for tile k0=0
#pragma unroll
  for (int q = 0; q < 8; ++q) {
    int gi = q * 256 + t, n = gi >> 3, o = gi & 7;
    const float* s = E + (size_t)(n0 + n) * D + o * 8;
    breg[2 * q] = *(const f32x4*)s;
    breg[2 * q + 1] = *(const f32x4*)(s + 4);
  }

#pragma unroll 1
  for (int k0 = 0; k0 < D; k0 += BK) {
    __syncthreads();  // previous compute done; LDS reusable

    // WRITE phase: convert staged E regs -> bf16 hi/lo LDS (swizzled)
#pragma unroll
    for (int q = 0; q < 8; ++q) {
      int gi = q * 256 + t, n = gi >> 3, o = gi & 7;
      f32x4 f0 = breg[2 * q], f1 = breg[2 * q + 1];
      unsigned int hw0, hw1, hw2, hw3, lw0, lw1, lw2, lw3;
      cvt_pair(f0.x, f0.y, hw0, lw0);
      cvt_pair(f0.z, f0.w, hw1, lw1);
      cvt_pair(f1.x, f1.y, hw2, lw2);
      cvt_pair(f1.z, f1.w, hw3, lw3);
      int off = n * 64 + ((o ^ (n & 7)) * 8);
      *(u32x4*)&BhS[off] = (u32x4){hw0, hw1, hw2, hw3};
      *(u32x4*)&BlS[off] = (u32x4){lw0, lw1, lw2, lw3};
    }
    // A tile staging (L2-resident bf16, loaded directly)
#pragma unroll
    for (int q = 0; q < 2; ++q) {
      int gi = q * 256 + t, m = gi >> 3, o = gi & 7;
      int off = m * 64 + ((o ^ (m & 7)) * 8);
      *(f32x4*)&AhS[off] = *(const f32x4*)(Ahg + (size_t)m * D + k0 + o * 8);
      *(f32x4*)&AlS[off] = *(const f32x4*)(Alg + (size_t)m * D + k0 + o * 8);
    }
    __syncthreads();

    // issue next tile's global loads early (hide HBM under MFMA)
    if (k0 + BK < D) {
      int kk = k0 + BK;
#pragma unroll
      for (int q = 0; q < 8; ++q) {
        int gi = q * 256 + t, n = gi >> 3, o = gi & 7;
        const float* s = E + (size_t)(n0 + n) * D + kk + o * 8;
        breg[2 * q] = *(const f32x4*)s;
        breg[2 * q + 1] = *(const f32x4*)(s + 4);
      }
    }

    // COMPUTE: 2 x K32 sub-steps
#pragma unroll
    for (int k32 = 0; k32 < 2; ++k32) {
      const int og = k32 * 4 + (lane >> 4);
      bf16x8 ah[4], al[4], bh[4], bl[4];
#pragma unroll
      for (int mf = 0; mf < 4; ++mf) {
        int r = mf * 16 + (lane & 15);
        int off = r * 64 + ((og ^ (r & 7)) * 8);
        ah[mf] = *(const bf16x8*)&AhS[off];
        al[mf] = *(const bf16x8*)&AlS[off];
      }
#pragma unroll
      for (int nf = 0; nf < 4; ++nf) {
        int n = wv * 64 + nf * 16 + (lane & 15);
        int off = n * 64 + ((og ^ (n & 7)) * 8);
        bh[nf] = *(const bf16x8*)&BhS[off];
        bl[nf] = *(const bf16x8*)&BlS[off];
      }
#pragma unroll
      for (int mf = 0; mf < 4; ++mf)
#pragma unroll
        for (int nf = 0; nf < 4; ++nf) {
          acc[mf][nf] = mfma16(ah[mf], bh[nf], acc[mf][nf]);
          acc[mf][nf] = mfma16(ah[mf], bl[nf], acc[mf][nf]);
          acc[mf][nf] = mfma16(al[mf], bh[nf], acc[mf][nf]);
        }
    }
  }

  // epilogue: D layout col=lane&15, row=(lane>>4)*4+reg
#pragma unroll
  for (int mf = 0; mf < 4; ++mf)
#pragma unroll
    for (int nf = 0; nf < 4; ++nf) {
      int v = n0 + wv * 64 + nf * 16 + (lane & 15);
      int rbase = mf * 16 + ((lane >> 4) << 2);
#pragma unroll
      for (int reg = 0; reg < 4; ++reg)
        outL[(size_t)(rbase + reg) * V + v] = acc[mf][nf][reg];
    }
}

// ---------- K2: per-batch radix-select of k-th largest + candidate gather ----------
__global__ __launch_bounds__(1024) void select_topk(
    const float* __restrict__ logits, const int* __restrict__ top_ks,
    float* __restrict__ cvals, int* __restrict__ cidx, int* __restrict__ ccnt, int V) {
  const int b = blockIdx.x;
  const float* row = logits + (size_t)b * V;
  const int tid = threadIdx.x;
  const int wv = tid >> 6;
  __shared__ unsigned int hist[16][256];
  __shared__ unsigned int s_prefix;
  __shared__ int s_needed;
  __shared__ int s_cnt;

  int k = top_ks[b];
  if (k < 1) k = 1;
  if (k > V) k = V;

  unsigned int prefix = 0;
  int needed = k;
  for (int pass = 0; pass < 4; ++pass) {
    for (int i = tid; i < 16 * 256; i += 1024) ((unsigned int*)hist)[i] = 0u;
    __syncthreads();
    const int shift = 24 - 8 * pass;
    for (int v = tid; v < V; v += 1024) {
      unsigned int u = f2ord(row[v]);
      bool ok = (pass == 0) || ((u >> (shift + 8)) == prefix);
      if (ok) atomicAdd(&hist[wv][(u >> shift) & 255u], 1u);
    }
    __syncthreads();
    if (tid < 256) {
      unsigned int s = 0;
      for (int w = 0; w < 16; ++w) s += hist[w][tid];
      hist[0][tid] = s;
    }
    __syncthreads();
    if (tid == 0) {
      unsigned int run = 0;
      int bin = 255;
      for (; bin >= 0; --bin) {
        unsigned int h = hist[0][bin];
        if (run + h >= (unsigned int)needed) break;
        run += h;
      }
      if (bin < 0) bin = 0;
      s_prefix = (prefix << 8) | (unsigned int)bin;
      s_needed = needed - (int)run;
    }
    __syncthreads();
    prefix = s_prefix;
    needed = s_needed;
    __syncthreads();
  }
  const unsigned int tau = prefix;

  if (tid == 0) s_cnt = 0;
  __syncthreads();
  for (int v = tid; v < V; v += 1024) {
    float x = row[v];
    if (f2ord(x) >= tau) {
      int p = atomicAdd(&s_cnt, 1);
      if (p < CAP) {
        cvals[(size_t)b * CAP + p] = x;
        cidx[(size_t)b * CAP + p] = v;
      }
    }
  }
  __syncthreads();
  if (tid == 0) ccnt[b] = (s_cnt < CAP) ? s_cnt : CAP;
}

// ---------- K3: sort candidates, top-p, probs scatter, gumbel argmax ----------
__global__ __launch_bounds__(1024) void finalize_k(
    const float* __restrict__ cvals, const int* __restrict__ cidx,
    const int* __restrict__ ccnt, const int* __restrict__ top_ks,
    const float* __restrict__ temps, const float* __restrict__ top_ps,
    float* __restrict__ out, int probs_base, int V, unsigned int half_n) {
  const int b = blockIdx.x, tid = threadIdx.x;
  __shared__ float vals[CAP];
  __shared__ int idxs[CAP];
  __shared__ float ex[1024];
  __shared__ float pr[1024];
  __shared__ float rsc[1024];
  __shared__ int rid[1024];
  __shared__ float s_S, s_S2;
  __shared__ int s_m;

  const int cnt = ccnt[b];
  int k = top_ks[b];
  if (k < 1) k = 1;
  if (k > V) k = V;
  int K = (k < cnt) ? k : cnt;
  if (K > 1024) K = 1024;

  for (int i = tid; i < CAP; i += 1024) {
    if (i < cnt) { vals[i] = cvals[(size_t)b * CAP + i]; idxs[i] = cidx[(size_t)b * CAP + i]; }
    else         { vals[i] = -INFINITY;                  idxs[i] = 0x7fffffff; }
  }
  __syncthreads();

  for (int size = 2; size <= CAP; size <<= 1) {
    for (int stride = size >> 1; stride > 0; stride >>= 1) {
      for (int i = tid; i < CAP; i += 1024) {
        int j = i ^ stride;
        if (j > i) {
          float vi = vals[i], vj = vals[j];
          int ii = idxs[i], ij = idxs[j];
          bool iBeforeJ = (vi > vj) || (vi == vj && ii < ij);
          bool up = ((i & size) == 0);
          if (up ? !iBeforeJ : iBeforeJ) {
            vals[i] = vj; idxs[i] = ij; vals[j] = vi; idxs[j] = ii;
          }
        }
      }
      __syncthreads();
    }
  }

  const float t = temps[b];
  const float tt = (t < 1e-5f) ? 1.0f : t;
  const float l0 = vals[0] / tt;
  for (int i = tid; i < K; i += 1024) ex[i] = expf(vals[i] / tt - l0);
  __syncthreads();

  if (tid == 0) {
    float S = 0.f;
    for (int i = 0; i < K; ++i) S += ex[i];
    s_S = S;
  }
  __syncthreads();
  const float S = s_S;
  for (int i = tid; i < K; i += 1024) pr[i] = ex[i] / S;
  __syncthreads();

  if (tid == 0) {
    float p = top_ps[b];
    int m;
    if (p >= 1.0f - 1e-5f) m = K;
    else {
      m = 1;
      float cum = pr[0];
      for (int i = 1; i < K; ++i) {
        cum += pr[i];
        if (cum <= p) m++; else break;
      }
    }
    s_m = m;
  }
  __syncthreads();
  const int m = s_m;

  {
    float loc = 0.f;
    for (int i = tid; i < m; i += 1024) loc += ex[i];
    rsc[tid] = loc;
    __syncthreads();
    for (int s = 512; s > 0; s >>= 1) {
      if (tid < s) rsc[tid] += rsc[tid + s];
      __syncthreads();
    }
    if (tid == 0) s_S2 = rsc[0];
    __syncthreads();
  }
  const float S2 = s_S2;

  for (int i = tid; i < m; i += 1024)
    out[(size_t)probs_base + (size_t)b * V + idxs[i]] = ex[i] / S2;

  float best = -INFINITY;
  int bestV = 0x7fffffff;
  for (int i = tid; i < m; i += 1024) {
    int vv = idxs[i];
    unsigned int flat = (unsigned int)b * (unsigned int)V + (unsigned int)vv;
    float g = gumbel_at(flat, half_n);
    float sc = vals[i] / tt + g;
    if (sc > best || (sc == best && vv < bestV)) { best = sc; bestV = vv; }
  }
  rsc[tid] = best; rid[tid] = bestV;
  __syncthreads();
  for (int s = 512; s > 0; s >>= 1) {
    if (tid < s) {
      float o = rsc[tid + s]; int oi = rid[tid + s];
      if (o > rsc[tid] || (o == rsc[tid] && oi < rid[tid])) { rsc[tid] = o; rid[tid] = oi; }
    }
    __syncthreads();
  }
  if (tid == 0) {
    int token = (t < 1e-5f) ? idxs[0] : rid[0];
    if (token < 0 || token >= V) token = 0;
    out[b] = (float)token;
  }
}

// ---------- launch ----------
extern "C" void kernel_launch(void* const* d_in, const int* in_sizes, int n_in,
                              void* d_out, int out_size, void* d_ws, size_t ws_size,
                              hipStream_t stream) {
  const float* hidden = (const float*)d_in[0];
  const float* emb    = (const float*)d_in[1];
  const int*   lti    = (const int*)d_in[2];
  const float* temps  = (const float*)d_in[3];
  const float* tops   = (const float*)d_in[4];
  const int*   topks  = (const int*)d_in[5];

  const int B = in_sizes[2];
  const int V = (int)(((long long)out_size - B) / B);
  const int D = in_sizes[1] / V;
  const int probs_base = out_size - B * V;  // = B
  const unsigned int half_n = (unsigned int)(((long long)B * V) / 2);

  float* out = (float*)d_out;

  char* ws = (char*)d_ws;
  size_t off = 0;
  unsigned short* Ah = (unsigned short*)(ws + off); off += (size_t)B * D * sizeof(unsigned short);
  unsigned short* Al = (unsigned short*)(ws + off); off += (size_t)B * D * sizeof(unsigned short);
  float* cvals = (float*)(ws + off); off += (size_t)B * CAP * sizeof(float);
  int* cidx = (int*)(ws + off);      off += (size_t)B * CAP * sizeof(int);
  int* ccnt = (int*)(ws + off);      off += (size_t)B * sizeof(int);
  (void)ws_size; (void)n_in;

  float* logits = out + probs_base;

  hipLaunchKernelGGL(gather_split, dim3(B), dim3(256), 0, stream, hidden, lti, Ah, Al, D);
  hipLaunchKernelGGL(gemm_mfma, dim3(V / BN), dim3(256), 0, stream, Ah, Al, emb, logits, D, V);
  hipLaunchKernelGGL(select_topk, dim3(B), dim3(1024), 0, stream, logits, topks, cvals, cidx, ccnt, V);
  hipMemsetAsync(d_out, 0, (size_t)out_size * sizeof(float), stream);
  hipLaunchKernelGGL(finalize_k, dim3(B), dim3(1024), 0, stream, cvals, cidx, ccnt,
                     topks, temps, tops, out, probs_base, V, half_n);
}

// Round 3
// 456.437 us; speedup vs baseline: 1.9713x; 1.2168x over previous
//
#include <hip/hip_runtime.h>
#include <hip/hip_bf16.h>
#include <math.h>

#define CAP 4096          // candidate capacity (gather covers ~1600-2600 typ.)
#define PRNG_PARTITIONABLE 1

typedef __attribute__((ext_vector_type(8))) short bf16x8;
typedef __attribute__((ext_vector_type(4))) float f32x4;
typedef __attribute__((ext_vector_type(4))) unsigned int u32x4;

// ---------- helpers ----------
__device__ __forceinline__ unsigned int f2ord(float x) {
  unsigned int u = __float_as_uint(x);
  return (u & 0x80000000u) ? ~u : (u | 0x80000000u);
}

__device__ __forceinline__ unsigned int rotl_u32(unsigned int x, int r) {
  return (x << r) | (x >> (32 - r));
}

__device__ float gumbel_at(unsigned int flat, unsigned int half_n) {
  const unsigned int ks0 = 0u;
  const unsigned int ks1 = 42u;
  const unsigned int ks2 = 0x1BD11BDAu ^ ks0 ^ ks1;
  unsigned int x0, x1;
#if PRNG_PARTITIONABLE
  x0 = 0u;
  x1 = flat;
#else
  unsigned int cnt = (flat < half_n) ? flat : (flat - half_n);
  x0 = cnt; x1 = cnt + half_n;
#endif
  x0 += ks0; x1 += ks1;
#define TF_R(r) { x0 += x1; x1 = rotl_u32(x1, r); x1 ^= x0; }
  TF_R(13) TF_R(15) TF_R(26) TF_R(6)
  x0 += ks1; x1 += ks2 + 1u;
  TF_R(17) TF_R(29) TF_R(16) TF_R(24)
  x0 += ks2; x1 += ks0 + 2u;
  TF_R(13) TF_R(15) TF_R(26) TF_R(6)
  x0 += ks0; x1 += ks1 + 3u;
  TF_R(17) TF_R(29) TF_R(16) TF_R(24)
  x0 += ks1; x1 += ks2 + 4u;
  TF_R(13) TF_R(15) TF_R(26) TF_R(6)
  x0 += ks2; x1 += ks0 + 5u;
#undef TF_R
#if PRNG_PARTITIONABLE
  unsigned int bits = x0 ^ x1;
#else
  unsigned int bits = (flat < half_n) ? x0 : x1;
#endif
  float f = __uint_as_float(0x3f800000u | (bits >> 9)) - 1.0f;
  float u = fmaxf(1e-20f, f + 1e-20f);
  return -logf(-logf(u));
}

__device__ __forceinline__ unsigned short f32_to_bf16_rne(float x) {
  unsigned int u = __float_as_uint(x);
  unsigned int r = u + 0x7fffu + ((u >> 16) & 1u);
  return (unsigned short)(r >> 16);
}
__device__ __forceinline__ float bf16u_to_f32(unsigned short h) {
  return __uint_as_float(((unsigned int)h) << 16);
}

__device__ __forceinline__ void cvt_pair(float a, float b, unsigned int& h, unsigned int& l) {
  float2 xf = make_float2(a, b);
  __hip_bfloat162 hh = __float22bfloat162_rn(xf);
  float2 hf = __bfloat1622float2(hh);
  __hip_bfloat162 ll = __float22bfloat162_rn(make_float2(a - hf.x, b - hf.y));
  __builtin_memcpy(&h, &hh, 4);
  __builtin_memcpy(&l, &ll, 4);
}

__device__ __forceinline__ f32x4 mfma16(bf16x8 a, bf16x8 b, f32x4 c) {
  return __builtin_amdgcn_mfma_f32_16x16x32_bf16(a, b, c, 0, 0, 0);
}

// ---------- K0: gather last-token rows + split to bf16 hi/lo ----------
__global__ void gather_split(const float* __restrict__ hidden, const int* __restrict__ lti,
                             unsigned short* __restrict__ Ah, unsigned short* __restrict__ Al,
                             int D) {
  int b = blockIdx.x;
  const float* src = hidden + (size_t)lti[b] * D;
  for (int i = threadIdx.x; i < D; i += blockDim.x) {
    float x = src[i];
    unsigned short h = f32_to_bf16_rne(x);
    float r = x - bf16u_to_f32(h);
    Ah[(size_t)b * D + i] = h;
    Al[(size_t)b * D + i] = f32_to_bf16_rne(r);
  }
}

// ---------- K1: logits = A @ E^T via bf16x3 MFMA, reg ping-pong pipeline ----
// BM=64, BN=128, BK=64. 4 waves; wave w owns n in [w*32, w*32+32).
// LDS bf16 [rows][64k], 16B-granule XOR swizzle: gran_phys = g ^ (row&7).
#define BN 128
#define BK 64
__global__ __launch_bounds__(256) void gemm_mfma(
    const unsigned short* __restrict__ Ahg, const unsigned short* __restrict__ Alg,
    const float* __restrict__ E, float* __restrict__ outL, int D, int V) {
  __shared__ __align__(16) unsigned short AhS[64 * 64];
  __shared__ __align__(16) unsigned short AlS[64 * 64];
  __shared__ __align__(16) unsigned short BhS[128 * 64];
  __shared__ __align__(16) unsigned short BlS[128 * 64];

  const int t = threadIdx.x;
  const int lane = t & 63;
  const int wv = t >> 6;
  const long n0 = (long)blockIdx.x * BN;
  const int am = t >> 2, ao = t & 3;  // A staging map: row am, 16-elem group ao

  f32x4 acc[4][2];
#pragma unroll
  for (int i = 0; i < 4; ++i)
#pragma unroll
    for (int j = 0; j < 2; ++j) acc[i][j] = (f32x4){0.f, 0.f, 0.f, 0.f};

  f32x4 bA[8], bB[8];
  bf16x8 aA[4], aB[4];

  auto LOAD = [&](f32x4* br, bf16x8* ar, int k0) {
#pragma unroll
    for (int q = 0; q < 4; ++q) {
      int gi = q * 256 + t, n = gi >> 3, o = gi & 7;
      const float* s = E + (size_t)(n0 + n) * D + k0 + o * 8;
      br[2 * q] = *(const f32x4*)s;
      br[2 * q + 1] = *(const f32x4*)(s + 4);
    }
    const unsigned short* ph = Ahg + (size_t)am * D + k0 + ao * 16;
    ar[0] = *(const bf16x8*)ph;
    ar[1] = *(const bf16x8*)(ph + 8);
    const unsigned short* pl = Alg + (size_t)am * D + k0 + ao * 16;
    ar[2] = *(const bf16x8*)pl;
    ar[3] = *(const bf16x8*)(pl + 8);
  };

  auto STAGE = [&](f32x4* br, bf16x8* ar) {
#pragma unroll
    for (int q = 0; q < 4; ++q) {
      int gi = q * 256 + t, n = gi >> 3, o = gi & 7;
      f32x4 f0 = br[2 * q], f1 = br[2 * q + 1];
      unsigned int hw0, hw1, hw2, hw3, lw0, lw1, lw2, lw3;
      cvt_pair(f0.x, f0.y, hw0, lw0);
      cvt_pair(f0.z, f0.w, hw1, lw1);
      cvt_pair(f1.x, f1.y, hw2, lw2);
      cvt_pair(f1.z, f1.w, hw3, lw3);
      int off = n * 64 + ((o ^ (n & 7)) * 8);
      *(u32x4*)&BhS[off] = (u32x4){hw0, hw1, hw2, hw3};
      *(u32x4*)&BlS[off] = (u32x4){lw0, lw1, lw2, lw3};
    }
    int g0 = ao * 2;
    int off0 = am * 64 + (((g0) ^ (am & 7)) * 8);
    int off1 = am * 64 + (((g0 + 1) ^ (am & 7)) * 8);
    *(bf16x8*)&AhS[off0] = ar[0];
    *(bf16x8*)&AhS[off1] = ar[1];
    *(bf16x8*)&AlS[off0] = ar[2];
    *(bf16x8*)&AlS[off1] = ar[3];
  };

  auto COMPUTE = [&]() {
#pragma unroll
    for (int k32 = 0; k32 < 2; ++k32) {
      const int og = k32 * 4 + (lane >> 4);
      bf16x8 ah[4], al[4], bh[2], bl[2];
#pragma unroll
      for (int mf = 0; mf < 4; ++mf) {
        int r = mf * 16 + (lane & 15);
        int off = r * 64 + ((og ^ (r & 7)) * 8);
        ah[mf] = *(const bf16x8*)&AhS[off];
        al[mf] = *(const bf16x8*)&AlS[off];
      }
#pragma unroll
      for (int nf = 0; nf < 2; ++nf) {
        int n = wv * 32 + nf * 16 + (lane & 15);
        int off = n * 64 + ((og ^ (n & 7)) * 8);
        bh[nf] = *(const bf16x8*)&BhS[off];
        bl[nf] = *(const bf16x8*)&BlS[off];
      }
#pragma unroll
      for (int mf = 0; mf < 4; ++mf)
#pragma unroll
        for (int nf = 0; nf < 2; ++nf) {
          acc[mf][nf] = mfma16(ah[mf], bh[nf], acc[mf][nf]);
          acc[mf][nf] = mfma16(ah[mf], bl[nf], acc[mf][nf]);
          acc[mf][nf] = mfma16(al[mf], bh[nf], acc[mf][nf]);
        }
    }
  };

  LOAD(bA, aA, 0);
#pragma unroll 1
  for (int k0 = 0; k0 < D; k0 += 2 * BK) {
    if (k0 + BK < D) LOAD(bB, aB, k0 + BK);       // issue-early: tile k+1
    __syncthreads();
    STAGE(bA, aA);
    __syncthreads();
    COMPUTE();
    if (k0 + 2 * BK < D) LOAD(bA, aA, k0 + 2 * BK);  // issue-early: tile k+2
    __syncthreads();
    STAGE(bB, aB);
    __syncthreads();
    COMPUTE();
  }

  // epilogue: D layout col=lane&15, row=(lane>>4)*4+reg
#pragma unroll
  for (int mf = 0; mf < 4; ++mf)
#pragma unroll
    for (int nf = 0; nf < 2; ++nf) {
      long v = n0 + wv * 32 + nf * 16 + (lane & 15);
      int rbase = mf * 16 + ((lane >> 4) << 2);
#pragma unroll
      for (int reg = 0; reg < 4; ++reg)
        outL[(size_t)(rbase + reg) * V + v] = acc[mf][nf][reg];
    }
}

// ---------- K2: 2-pass candidate select (8-bit hist + gather) ----------
__global__ __launch_bounds__(1024) void select_topk(
    const float* __restrict__ logits, const int* __restrict__ top_ks,
    float* __restrict__ cvals, int* __restrict__ cidx, int* __restrict__ ccnt, int V) {
  const int b = blockIdx.x;
  const float* row = logits + (size_t)b * V;
  const int tid = threadIdx.x;
  const int wv = tid >> 6;
  __shared__ unsigned int hist[16][256];
  __shared__ int s_bin;
  __shared__ int s_cnt;

  int k = top_ks[b];
  if (k < 1) k = 1;
  if (k > V) k = V;

  for (int i = tid; i < 16 * 256; i += 1024) ((unsigned int*)hist)[i] = 0u;
  __syncthreads();

  // pass 1: top-byte histogram, f32x4 vectorized
  for (int i = tid * 4; i < V; i += 4096) {
    f32x4 v4 = *(const f32x4*)(row + i);
    atomicAdd(&hist[wv][f2ord(v4.x) >> 24], 1u);
    atomicAdd(&hist[wv][f2ord(v4.y) >> 24], 1u);
    atomicAdd(&hist[wv][f2ord(v4.z) >> 24], 1u);
    atomicAdd(&hist[wv][f2ord(v4.w) >> 24], 1u);
  }
  __syncthreads();
  if (tid < 256) {
    unsigned int s = 0;
    for (int w = 0; w < 16; ++w) s += hist[w][tid];
    hist[0][tid] = s;
  }
  __syncthreads();
  if (tid == 0) {
    unsigned int run = 0;
    int bin = 255;
    for (; bin >= 0; --bin) {
      run += hist[0][bin];
      if (run >= (unsigned int)k) break;
    }
    s_bin = (bin < 0) ? 0 : bin;
    s_cnt = 0;
  }
  __syncthreads();
  const unsigned int binq = (unsigned int)s_bin;

  // pass 2: gather all elements with top byte >= bin*
  for (int i = tid * 4; i < V; i += 4096) {
    f32x4 v4 = *(const f32x4*)(row + i);
#pragma unroll
    for (int e = 0; e < 4; ++e) {
      float x = v4[e];
      if ((f2ord(x) >> 24) >= binq) {
        int p = atomicAdd(&s_cnt, 1);
        if (p < CAP) {
          cvals[(size_t)b * CAP + p] = x;
          cidx[(size_t)b * CAP + p] = i + e;
        }
      }
    }
  }
  __syncthreads();
  if (tid == 0) ccnt[b] = (s_cnt < CAP) ? s_cnt : CAP;
}

// ---------- K3: sort candidates, top-k, top-p, probs scatter, gumbel ----------
__global__ __launch_bounds__(1024) void finalize_k(
    const float* __restrict__ cvals, const int* __restrict__ cidx,
    const int* __restrict__ ccnt, const int* __restrict__ top_ks,
    const float* __restrict__ temps, const float* __restrict__ top_ps,
    float* __restrict__ out, int probs_base, int V, unsigned int half_n) {
  const int b = blockIdx.x, tid = threadIdx.x;
  __shared__ float vals[CAP];
  __shared__ int idxs[CAP];
  __shared__ float ex[1024];
  __shared__ float pr[1024];
  __shared__ float rsc[1024];
  __shared__ int rid[1024];
  __shared__ float s_S, s_S2;
  __shared__ int s_m;

  const int cnt = ccnt[b];
  int k = top_ks[b];
  if (k < 1) k = 1;
  if (k > V) k = V;
  int K = (k < cnt) ? k : cnt;
  if (K > 1024) K = 1024;

  for (int i = tid; i < CAP; i += 1024) {
    if (i < cnt) { vals[i] = cvals[(size_t)b * CAP + i]; idxs[i] = cidx[(size_t)b * CAP + i]; }
    else         { vals[i] = -INFINITY;                  idxs[i] = 0x7fffffff; }
  }
  __syncthreads();

  // bitonic sort: (val desc, idx asc) == stable argsort(-logits)
  for (int size = 2; size <= CAP; size <<= 1) {
    for (int stride = size >> 1; stride > 0; stride >>= 1) {
      for (int i = tid; i < CAP; i += 1024) {
        int j = i ^ stride;
        if (j > i) {
          float vi = vals[i], vj = vals[j];
          int ii = idxs[i], ij = idxs[j];
          bool iBeforeJ = (vi > vj) || (vi == vj && ii < ij);
          bool up = ((i & size) == 0);
          if (up ? !iBeforeJ : iBeforeJ) {
            vals[i] = vj; idxs[i] = ij; vals[j] = vi; idxs[j] = ii;
          }
        }
      }
      __syncthreads();
    }
  }

  const float t = temps[b];
  const float tt = (t < 1e-5f) ? 1.0f : t;
  const float l0 = vals[0] / tt;
  for (int i = tid; i < K; i += 1024) ex[i] = expf(vals[i] / tt - l0);
  __syncthreads();

  if (tid == 0) {
    float S = 0.f;
    for (int i = 0; i < K; ++i) S += ex[i];
    s_S = S;
  }
  __syncthreads();
  const float S = s_S;
  for (int i = tid; i < K; i += 1024) pr[i] = ex[i] / S;
  __syncthreads();

  if (tid == 0) {
    float p = top_ps[b];
    int m;
    if (p >= 1.0f - 1e-5f) m = K;
    else {
      m = 1;
      float cum = pr[0];
      for (int i = 1; i < K; ++i) {
        cum += pr[i];
        if (cum <= p) m++; else break;
      }
    }
    s_m = m;
  }
  __syncthreads();
  const int m = s_m;

  {
    float loc = 0.f;
    for (int i = tid; i < m; i += 1024) loc += ex[i];
    rsc[tid] = loc;
    __syncthreads();
    for (int s = 512; s > 0; s >>= 1) {
      if (tid < s) rsc[tid] += rsc[tid + s];
      __syncthreads();
    }
    if (tid == 0) s_S2 = rsc[0];
    __syncthreads();
  }
  const float S2 = s_S2;

  for (int i = tid; i < m; i += 1024)
    out[(size_t)probs_base + (size_t)b * V + idxs[i]] = ex[i] / S2;

  float best = -INFINITY;
  int bestV = 0x7fffffff;
  for (int i = tid; i < m; i += 1024) {
    int vv = idxs[i];
    unsigned int flat = (unsigned int)b * (unsigned int)V + (unsigned int)vv;
    float g = gumbel_at(flat, half_n);
    float sc = vals[i] / tt + g;
    if (sc > best || (sc == best && vv < bestV)) { best = sc; bestV = vv; }
  }
  rsc[tid] = best; rid[tid] = bestV;
  __syncthreads();
  for (int s = 512; s > 0; s >>= 1) {
    if (tid < s) {
      float o = rsc[tid + s]; int oi = rid[tid + s];
      if (o > rsc[tid] || (o == rsc[tid] && oi < rid[tid])) { rsc[tid] = o; rid[tid] = oi; }
    }
    __syncthreads();
  }
  if (tid == 0) {
    int token = (t < 1e-5f) ? idxs[0] : rid[0];
    if (token < 0 || token >= V) token = 0;
    out[b] = (float)token;
  }
}

// ---------- launch ----------
extern "C" void kernel_launch(void* const* d_in, const int* in_sizes, int n_in,
                              void* d_out, int out_size, void* d_ws, size_t ws_size,
                              hipStream_t stream) {
  const float* hidden = (const float*)d_in[0];
  const float* emb    = (const float*)d_in[1];
  const int*   lti    = (const int*)d_in[2];
  const float* temps  = (const float*)d_in[3];
  const float* tops   = (const float*)d_in[4];
  const int*   topks  = (const int*)d_in[5];

  const int B = in_sizes[2];
  const int V = (int)(((long long)out_size - B) / B);
  const int D = in_sizes[1] / V;
  const int probs_base = out_size - B * V;  // = B
  const unsigned int half_n = (unsigned int)(((long long)B * V) / 2);

  float* out = (float*)d_out;

  char* ws = (char*)d_ws;
  size_t off = 0;
  unsigned short* Ah = (unsigned short*)(ws + off); off += (size_t)B * D * sizeof(unsigned short);
  unsigned short* Al = (unsigned short*)(ws + off); off += (size_t)B * D * sizeof(unsigned short);
  float* cvals = (float*)(ws + off); off += (size_t)B * CAP * sizeof(float);
  int* cidx = (int*)(ws + off);      off += (size_t)B * CAP * sizeof(int);
  int* ccnt = (int*)(ws + off);      off += (size_t)B * sizeof(int);
  (void)ws_size; (void)n_in;

  float* logits = out + probs_base;

  hipLaunchKernelGGL(gather_split, dim3(B), dim3(256), 0, stream, hidden, lti, Ah, Al, D);
  hipLaunchKernelGGL(gemm_mfma, dim3(V / BN), dim3(256), 0, stream, Ah, Al, emb, logits, D, V);
  hipLaunchKernelGGL(select_topk, dim3(B), dim3(1024), 0, stream, logits, topks, cvals, cidx, ccnt, V);
  hipMemsetAsync(d_out, 0, (size_t)out_size * sizeof(float), stream);
  hipLaunchKernelGGL(finalize_k, dim3(B), dim3(1024), 0, stream, cvals, cidx, ccnt,
                     topks, temps, tops, out, probs_base, V, half_n);
}

// Round 5
// 435.213 us; speedup vs baseline: 2.0675x; 1.0488x over previous
//
#include <hip/hip_runtime.h>
#include <hip/hip_bf16.h>
#include <math.h>

#define CAP 2048
#define PRNG_PARTITIONABLE 1

typedef __attribute__((ext_vector_type(8))) short bf16x8;
typedef __attribute__((ext_vector_type(4))) float f32x4;
typedef __attribute__((ext_vector_type(4))) unsigned int u32x4;

union B8U4 { u32x4 u; bf16x8 b; };

// ---------- helpers ----------
__device__ __forceinline__ unsigned int f2ord(float x) {
  unsigned int u = __float_as_uint(x);
  return (u & 0x80000000u) ? ~u : (u | 0x80000000u);
}

__device__ __forceinline__ unsigned int rotl_u32(unsigned int x, int r) {
  return (x << r) | (x >> (32 - r));
}

__device__ float gumbel_at(unsigned int flat, unsigned int half_n) {
  const unsigned int ks0 = 0u;
  const unsigned int ks1 = 42u;
  const unsigned int ks2 = 0x1BD11BDAu ^ ks0 ^ ks1;
  unsigned int x0, x1;
#if PRNG_PARTITIONABLE
  x0 = 0u;
  x1 = flat;
#else
  unsigned int cnt = (flat < half_n) ? flat : (flat - half_n);
  x0 = cnt; x1 = cnt + half_n;
#endif
  x0 += ks0; x1 += ks1;
#define TF_R(r) { x0 += x1; x1 = rotl_u32(x1, r); x1 ^= x0; }
  TF_R(13) TF_R(15) TF_R(26) TF_R(6)
  x0 += ks1; x1 += ks2 + 1u;
  TF_R(17) TF_R(29) TF_R(16) TF_R(24)
  x0 += ks2; x1 += ks0 + 2u;
  TF_R(13) TF_R(15) TF_R(26) TF_R(6)
  x0 += ks0; x1 += ks1 + 3u;
  TF_R(17) TF_R(29) TF_R(16) TF_R(24)
  x0 += ks1; x1 += ks2 + 4u;
  TF_R(13) TF_R(15) TF_R(26) TF_R(6)
  x0 += ks2; x1 += ks0 + 5u;
#undef TF_R
#if PRNG_PARTITIONABLE
  unsigned int bits = x0 ^ x1;
#else
  unsigned int bits = (flat < half_n) ? x0 : x1;
#endif
  float f = __uint_as_float(0x3f800000u | (bits >> 9)) - 1.0f;
  float u = fmaxf(1e-20f, f + 1e-20f);
  return -logf(-logf(u));
}

__device__ __forceinline__ unsigned short f32_to_bf16_rne(float x) {
  unsigned int u = __float_as_uint(x);
  unsigned int r = u + 0x7fffu + ((u >> 16) & 1u);
  return (unsigned short)(r >> 16);
}
__device__ __forceinline__ float bf16u_to_f32(unsigned short h) {
  return __uint_as_float(((unsigned int)h) << 16);
}

// pack 2 f32 -> (hi bf16 pair, lo bf16 pair) as two u32 words
struct HL { unsigned int h, l; };
__device__ __forceinline__ HL cvt_pair(float a, float b) {
  float2 xf = make_float2(a, b);
  __hip_bfloat162 hh = __float22bfloat162_rn(xf);
  float2 hf = __bfloat1622float2(hh);
  __hip_bfloat162 ll = __float22bfloat162_rn(make_float2(a - hf.x, b - hf.y));
  HL r;
  __builtin_memcpy(&r.h, &hh, 4);
  __builtin_memcpy(&r.l, &ll, 4);
  return r;
}

__device__ __forceinline__ f32x4 mfma16(bf16x8 a, bf16x8 b, f32x4 c) {
  return __builtin_amdgcn_mfma_f32_16x16x32_bf16(a, b, c, 0, 0, 0);
}

// ---------- K0: gather last-token rows + split to bf16 hi/lo ----------
__global__ void gather_split(const float* __restrict__ hidden, const int* __restrict__ lti,
                             unsigned short* __restrict__ Ah, unsigned short* __restrict__ Al,
                             int D) {
  int b = blockIdx.x;
  const float* src = hidden + (size_t)lti[b] * D;
  for (int i = threadIdx.x; i < D; i += blockDim.x) {
    float x = src[i];
    unsigned short h = f32_to_bf16_rne(x);
    float r = x - bf16u_to_f32(h);
    Ah[(size_t)b * D + i] = h;
    Al[(size_t)b * D + i] = f32_to_bf16_rne(r);
  }
}

// ---------- K1: logits = A @ E^T via bf16x3 MFMA ----------
// BM=64, BN=128, BK=64. 4 waves; wave w owns n in [w*32, w*32+32).
// B stored as raw f32 in LDS (convert-on-read, under MFMA shadow).
// B swizzle: 16B grans (4 f32), 16/row, phys_gran = g ^ (n&7).
// A bf16 hi/lo LDS: 16B grans (8 bf16), 8/row, phys_gran = g ^ (r&7).
#define BN 128
#define BK 64
__global__ __launch_bounds__(256) void gemm_mfma(
    const unsigned short* __restrict__ Ahg, const unsigned short* __restrict__ Alg,
    const float* __restrict__ E, float* __restrict__ outL, int D, int V) {
  __shared__ __align__(16) float BS[128 * 64];
  __shared__ __align__(16) unsigned short AhS[64 * 64];
  __shared__ __align__(16) unsigned short AlS[64 * 64];

  const int t = threadIdx.x;
  const int lane = t & 63;
  const int wv = t >> 6;
  const long n0 = (long)blockIdx.x * BN;
  const int am = t >> 2, ao = t & 3;  // A staging: row am, 16-elem group ao

  f32x4 acc[4][2];
#pragma unroll
  for (int i = 0; i < 4; ++i)
#pragma unroll
    for (int j = 0; j < 2; ++j) acc[i][j] = (f32x4){0.f, 0.f, 0.f, 0.f};

  f32x4 bA[8], bB[8];
  bf16x8 aA[4], aB[4];

  auto LOAD = [&](f32x4* br, bf16x8* ar, int k0) {
#pragma unroll
    for (int q = 0; q < 4; ++q) {
      int gi = q * 256 + t, n = gi >> 3, o = gi & 7;
      const float* s = E + (size_t)(n0 + n) * D + k0 + o * 8;
      br[2 * q] = *(const f32x4*)s;
      br[2 * q + 1] = *(const f32x4*)(s + 4);
    }
    const unsigned short* ph = Ahg + (size_t)am * D + k0 + ao * 16;
    ar[0] = *(const bf16x8*)ph;
    ar[1] = *(const bf16x8*)(ph + 8);
    const unsigned short* pl = Alg + (size_t)am * D + k0 + ao * 16;
    ar[2] = *(const bf16x8*)pl;
    ar[3] = *(const bf16x8*)(pl + 8);
  };

  auto STAGE = [&](f32x4* br, bf16x8* ar) {
#pragma unroll
    for (int q = 0; q < 4; ++q) {
      int gi = q * 256 + t, n = gi >> 3, o = gi & 7;
      int pg0 = (2 * o) ^ (n & 7);
      int pg1 = (2 * o + 1) ^ (n & 7);
      *(f32x4*)&BS[n * 64 + pg0 * 4] = br[2 * q];
      *(f32x4*)&BS[n * 64 + pg1 * 4] = br[2 * q + 1];
    }
    int g0 = ao * 2;
    int off0 = am * 64 + ((g0 ^ (am & 7)) * 8);
    int off1 = am * 64 + (((g0 + 1) ^ (am & 7)) * 8);
    *(bf16x8*)&AhS[off0] = ar[0];
    *(bf16x8*)&AhS[off1] = ar[1];
    *(bf16x8*)&AlS[off0] = ar[2];
    *(bf16x8*)&AlS[off1] = ar[3];
  };

  auto COMPUTE = [&]() {
#pragma unroll
    for (int k32 = 0; k32 < 2; ++k32) {
      const int og = k32 * 4 + (lane >> 4);
      bf16x8 ah[4], al[4], bh[2], bl[2];
#pragma unroll
      for (int mf = 0; mf < 4; ++mf) {
        int r = mf * 16 + (lane & 15);
        int off = r * 64 + ((og ^ (r & 7)) * 8);
        ah[mf] = *(const bf16x8*)&AhS[off];
        al[mf] = *(const bf16x8*)&AlS[off];
      }
#pragma unroll
      for (int nf = 0; nf < 2; ++nf) {
        int n = wv * 32 + nf * 16 + (lane & 15);
        int pg0 = (2 * og) ^ (n & 7);
        int pg1 = (2 * og + 1) ^ (n & 7);
        f32x4 v0 = *(const f32x4*)&BS[n * 64 + pg0 * 4];
        f32x4 v1 = *(const f32x4*)&BS[n * 64 + pg1 * 4];
        HL p0 = cvt_pair(v0.x, v0.y);
        HL p1 = cvt_pair(v0.z, v0.w);
        HL p2 = cvt_pair(v1.x, v1.y);
        HL p3 = cvt_pair(v1.z, v1.w);
        B8U4 hb, lb;
        hb.u = (u32x4){p0.h, p1.h, p2.h, p3.h};
        lb.u = (u32x4){p0.l, p1.l, p2.l, p3.l};
        bh[nf] = hb.b;
        bl[nf] = lb.b;
      }
      __builtin_amdgcn_s_setprio(1);
#pragma unroll
      for (int mf = 0; mf < 4; ++mf)
#pragma unroll
        for (int nf = 0; nf < 2; ++nf) {
          acc[mf][nf] = mfma16(ah[mf], bh[nf], acc[mf][nf]);
          acc[mf][nf] = mfma16(ah[mf], bl[nf], acc[mf][nf]);
          acc[mf][nf] = mfma16(al[mf], bh[nf], acc[mf][nf]);
        }
      __builtin_amdgcn_s_setprio(0);
    }
  };

  LOAD(bA, aA, 0);
#pragma unroll 1
  for (int k0 = 0; k0 < D; k0 += 2 * BK) {
    if (k0 + BK < D) LOAD(bB, aB, k0 + BK);          // issue-early: tile k+1
    __syncthreads();
    STAGE(bA, aA);
    __syncthreads();
    COMPUTE();
    if (k0 + 2 * BK < D) LOAD(bA, aA, k0 + 2 * BK);  // issue-early: tile k+2
    __syncthreads();
    STAGE(bB, aB);
    __syncthreads();
    COMPUTE();
  }

  // epilogue: D layout col=lane&15, row=(lane>>4)*4+reg
#pragma unroll
  for (int mf = 0; mf < 4; ++mf)
#pragma unroll
    for (int nf = 0; nf < 2; ++nf) {
      long v = n0 + wv * 32 + nf * 16 + (lane & 15);
      int rbase = mf * 16 + ((lane >> 4) << 2);
#pragma unroll
      for (int reg = 0; reg < 4; ++reg)
        outL[(size_t)(rbase + reg) * V + v] = acc[mf][nf][reg];
    }
}

// ---------- K2: candidate select, 16-bit two-level threshold ----------
__global__ __launch_bounds__(1024) void select_topk(
    const float* __restrict__ logits, const int* __restrict__ top_ks,
    float* __restrict__ cvals, int* __restrict__ cidx, int* __restrict__ ccnt, int V) {
  const int b = blockIdx.x;
  const float* row = logits + (size_t)b * V;
  const int tid = threadIdx.x;
  const int wv = tid >> 6;
  __shared__ unsigned int hist[16][256];
  __shared__ int s_bin, s_cntGT, s_refine;
  __shared__ unsigned int s_tau;
  __shared__ int s_cnt;

  int k = top_ks[b];
  if (k < 1) k = 1;
  if (k > V) k = V;

  for (int i = tid; i < 16 * 256; i += 1024) ((unsigned int*)hist)[i] = 0u;
  __syncthreads();

  // pass 1: top-byte histogram (f32x4 vectorized)
  for (int i = tid * 4; i < V; i += 4096) {
    f32x4 v4 = *(const f32x4*)(row + i);
    atomicAdd(&hist[wv][f2ord(v4.x) >> 24], 1u);
    atomicAdd(&hist[wv][f2ord(v4.y) >> 24], 1u);
    atomicAdd(&hist[wv][f2ord(v4.z) >> 24], 1u);
    atomicAdd(&hist[wv][f2ord(v4.w) >> 24], 1u);
  }
  __syncthreads();
  if (tid < 256) {
    unsigned int s = 0;
    for (int w = 0; w < 16; ++w) s += hist[w][tid];
    hist[0][tid] = s;
  }
  __syncthreads();
  if (tid == 0) {
    unsigned int run = 0;
    int bin = 255;
    for (; bin >= 0; --bin) {
      unsigned int h = hist[0][bin];
      if (run + h >= (unsigned int)k) {
        s_bin = bin;
        s_cntGT = (int)run;
        s_refine = (run + h > (unsigned int)CAP) ? 1 : 0;
        break;
      }
      run += h;
    }
    if (bin < 0) { s_bin = 0; s_cntGT = 0; s_refine = 0; }
    s_cnt = 0;
  }
  __syncthreads();
  const unsigned int binq = (unsigned int)s_bin;
  unsigned int tau16;

  if (s_refine) {
    // pass 1b: 2nd-byte histogram restricted to elements in the boundary bin
    __syncthreads();
    for (int i = tid; i < 16 * 256; i += 1024) ((unsigned int*)hist)[i] = 0u;
    __syncthreads();
    for (int i = tid * 4; i < V; i += 4096) {
      f32x4 v4 = *(const f32x4*)(row + i);
#pragma unroll
      for (int e = 0; e < 4; ++e) {
        unsigned int u = f2ord(v4[e]);
        if ((u >> 24) == binq) atomicAdd(&hist[wv][(u >> 16) & 255u], 1u);
      }
    }
    __syncthreads();
    if (tid < 256) {
      unsigned int s = 0;
      for (int w = 0; w < 16; ++w) s += hist[w][tid];
      hist[0][tid] = s;
    }
    __syncthreads();
    if (tid == 0) {
      int need = k - s_cntGT;  // >= 1
      unsigned int run = 0;
      int sub = 255;
      for (; sub >= 0; --sub) {
        unsigned int h = hist[0][sub];
        if (run + h >= (unsigned int)need) break;
        run += h;
      }
      if (sub < 0) sub = 0;
      s_tau = (binq << 8) | (unsigned int)sub;
    }
    __syncthreads();
    tau16 = s_tau;
  } else {
    tau16 = binq << 8;
  }

  // pass 2: gather all elements with 16-bit ordered prefix >= tau16
  for (int i = tid * 4; i < V; i += 4096) {
    f32x4 v4 = *(const f32x4*)(row + i);
#pragma unroll
    for (int e = 0; e < 4; ++e) {
      float x = v4[e];
      if ((f2ord(x) >> 16) >= tau16) {
        int p = atomicAdd(&s_cnt, 1);
        if (p < CAP) {
          cvals[(size_t)b * CAP + p] = x;
          cidx[(size_t)b * CAP + p] = i + e;
        }
      }
    }
  }
  __syncthreads();
  if (tid == 0) ccnt[b] = (s_cnt < CAP) ? s_cnt : CAP;
}

// ---------- K3: zero row, sort candidates, top-k/top-p, scatter, gumbel ----
__global__ __launch_bounds__(1024) void finalize_k(
    const float* __restrict__ cvals, const int* __restrict__ cidx,
    const int* __restrict__ ccnt, const int* __restrict__ top_ks,
    const float* __restrict__ temps, const float* __restrict__ top_ps,
    float* __restrict__ out, int probs_base, int V, unsigned int half_n) {
  const int b = blockIdx.x, tid = threadIdx.x;
  __shared__ float vals[CAP];
  __shared__ int idxs[CAP];
  __shared__ float ex[1024];
  __shared__ float pr[1024];
  __shared__ float rsc[1024];
  __shared__ int rid[1024];
  __shared__ float s_S, s_S2;
  __shared__ int s_m;

  const int cnt = ccnt[b];
  int k = top_ks[b];
  if (k < 1) k = 1;
  if (k > V) k = V;
  int K = (k < cnt) ? k : cnt;
  if (K > 1024) K = 1024;

  for (int i = tid; i < CAP; i += 1024) {
    if (i < cnt) { vals[i] = cvals[(size_t)b * CAP + i]; idxs[i] = cidx[(size_t)b * CAP + i]; }
    else         { vals[i] = -INFINITY;                  idxs[i] = 0x7fffffff; }
  }

  // zero this row's probs (replaces global memset; overlaps with sort)
  {
    float* rowp = out + (size_t)probs_base + (size_t)b * V;
    const f32x4 z = (f32x4){0.f, 0.f, 0.f, 0.f};
    for (int i = tid * 4; i < V; i += 4096) *(f32x4*)(rowp + i) = z;
  }
  __syncthreads();

  // bitonic sort: (val desc, idx asc) == stable argsort(-logits)
  for (int size = 2; size <= CAP; size <<= 1) {
    for (int stride = size >> 1; stride > 0; stride >>= 1) {
      for (int i = tid; i < CAP; i += 1024) {
        int j = i ^ stride;
        if (j > i) {
          float vi = vals[i], vj = vals[j];
          int ii = idxs[i], ij = idxs[j];
          bool iBeforeJ = (vi > vj) || (vi == vj && ii < ij);
          bool up = ((i & size) == 0);
          if (up ? !iBeforeJ : iBeforeJ) {
            vals[i] = vj; idxs[i] = ij; vals[j] = vi; idxs[j] = ii;
          }
        }
      }
      __syncthreads();
    }
  }

  const float t = temps[b];
  const float tt = (t < 1e-5f) ? 1.0f : t;
  const float l0 = vals[0] / tt;
  for (int i = tid; i < K; i += 1024) ex[i] = expf(vals[i] / tt - l0);
  __syncthreads();

  if (tid == 0) {
    float S = 0.f;
    for (int i = 0; i < K; ++i) S += ex[i];
    s_S = S;
  }
  __syncthreads();
  const float S = s_S;
  for (int i = tid; i < K; i += 1024) pr[i] = ex[i] / S;
  __syncthreads();

  if (tid == 0) {
    float p = top_ps[b];
    int m;
    if (p >= 1.0f - 1e-5f) m = K;
    else {
      m = 1;
      float cum = pr[0];
      for (int i = 1; i < K; ++i) {
        cum += pr[i];
        if (cum <= p) m++; else break;
      }
    }
    s_m = m;
  }
  __syncthreads();
  const int m = s_m;

  {
    float loc = 0.f;
    for (int i = tid; i < m; i += 1024) loc += ex[i];
    rsc[tid] = loc;
    __syncthreads();
    for (int s = 512; s > 0; s >>= 1) {
      if (tid < s) rsc[tid] += rsc[tid + s];
      __syncthreads();
    }
    if (tid == 0) s_S2 = rsc[0];
    __syncthreads();
  }
  const float S2 = s_S2;

  for (int i = tid; i < m; i += 1024)
    out[(size_t)probs_base + (size_t)b * V + idxs[i]] = ex[i] / S2;

  float best = -INFINITY;
  int bestV = 0x7fffffff;
  for (int i = tid; i < m; i += 1024) {
    int vv = idxs[i];
    unsigned int flat = (unsigned int)b * (unsigned int)V + (unsigned int)vv;
    float g = gumbel_at(flat, half_n);
    float sc = vals[i] / tt + g;
    if (sc > best || (sc == best && vv < bestV)) { best = sc; bestV = vv; }
  }
  rsc[tid] = best; rid[tid] = bestV;
  __syncthreads();
  for (int s = 512; s > 0; s >>= 1) {
    if (tid < s) {
      float o = rsc[tid + s]; int oi = rid[tid + s];
      if (o > rsc[tid] || (o == rsc[tid] && oi < rid[tid])) { rsc[tid] = o; rid[tid] = oi; }
    }
    __syncthreads();
  }
  if (tid == 0) {
    int token = (t < 1e-5f) ? idxs[0] : rid[0];
    if (token < 0 || token >= V) token = 0;
    out[b] = (float)token;
  }
}

// ---------- launch ----------
extern "C" void kernel_launch(void* const* d_in, const int* in_sizes, int n_in,
                              void* d_out, int out_size, void* d_ws, size_t ws_size,
                              hipStream_t stream) {
  const float* hidden = (const float*)d_in[0];
  const float* emb    = (const float*)d_in[1];
  const int*   lti    = (const int*)d_in[2];
  const float* temps  = (const float*)d_in[3];
  const float* tops   = (const float*)d_in[4];
  const int*   topks  = (const int*)d_in[5];

  const int B = in_sizes[2];
  const int V = (int)(((long long)out_size - B) / B);
  const int D = in_sizes[1] / V;
  const int probs_base = out_size - B * V;  // = B
  const unsigned int half_n = (unsigned int)(((long long)B * V) / 2);

  float* out = (float*)d_out;

  char* ws = (char*)d_ws;
  size_t off = 0;
  unsigned short* Ah = (unsigned short*)(ws + off); off += (size_t)B * D * sizeof(unsigned short);
  unsigned short* Al = (unsigned short*)(ws + off); off += (size_t)B * D * sizeof(unsigned short);
  float* cvals = (float*)(ws + off); off += (size_t)B * CAP * sizeof(float);
  int* cidx = (int*)(ws + off);      off += (size_t)B * CAP * sizeof(int);
  int* ccnt = (int*)(ws + off);      off += (size_t)B * sizeof(int);
  (void)ws_size; (void)n_in;

  float* logits = out + probs_base;

  hipLaunchKernelGGL(gather_split, dim3(B), dim3(256), 0, stream, hidden, lti, Ah, Al, D);
  hipLaunchKernelGGL(gemm_mfma, dim3(V / BN), dim3(256), 0, stream, Ah, Al, emb, logits, D, V);
  hipLaunchKernelGGL(select_topk, dim3(B), dim3(1024), 0, stream, logits, topks, cvals, cidx, ccnt, V);
  hipLaunchKernelGGL(finalize_k, dim3(B), dim3(1024), 0, stream, cvals, cidx, ccnt,
                     topks, temps, tops, out, probs_base, V, half_n);
}